// Round 4
// baseline (124.834 us; speedup 1.0000x reference)
//
#include <hip/hip_runtime.h>

typedef __attribute__((ext_vector_type(8))) short short8;
typedef __attribute__((ext_vector_type(4))) float f32x4;

#define N_ROWS 32768
#define D 128
#define K_EMB 1024

// ws layout: fragment-permuted bf16 E (hi/lo interleaved per kc) + 1024*||e||^2
#define WS_EF 0                        // 512 KB
#define WS_EN (K_EMB * D * 2 * 2)      // 524288

__device__ __forceinline__ unsigned short f2bf(float f) {
    unsigned u = __float_as_uint(f);
    u += 0x7fffu + ((u >> 16) & 1u);   // RNE to bf16
    return (unsigned short)(u >> 16);
}

// ---- prep: emb -> fragment-linear split-bf16 + en*1024 ; zero loss ----
// short8 index: ct*512 + (kc*2+h)*64 + quad*16 + l15
//   holds E[col = ct*16+l15][dims kc*32+quad*8 .. +8], h=0 hi, h=1 lo
__global__ __launch_bounds__(256) void vq_prep(const float* __restrict__ emb,
                                               short8* __restrict__ Ef,
                                               float* __restrict__ en1024,
                                               float* __restrict__ loss_slot) {
    int t = blockIdx.x * 256 + threadIdx.x;   // 16384: 1024 cols x 16 parts
    int col = t >> 4, part = t & 15;          // dims part*8 .. part*8+8
    int kc = part >> 2, quad = part & 3;
    int ct = col >> 4, l15 = col & 15;

    const float4* e4 = (const float4*)(emb + (size_t)col * D + part * 8);
    float4 a = e4[0], b = e4[1];
    float xv[8] = {a.x, a.y, a.z, a.w, b.x, b.y, b.z, b.w};
    short8 sh, sl;
    float s = 0.0f;
    #pragma unroll
    for (int j = 0; j < 8; ++j) {
        float f = xv[j];
        s += f * f;
        unsigned short hb = f2bf(f);
        float hf = __uint_as_float(((unsigned)hb) << 16);
        sh[j] = (short)hb;
        sl[j] = (short)f2bf(f - hf);
    }
    int base = ct * 512 + quad * 16 + l15;
    Ef[base + (kc * 2 + 0) * 64] = sh;
    Ef[base + (kc * 2 + 1) * 64] = sl;
    #pragma unroll
    for (int off = 8; off; off >>= 1) s += __shfl_down(s, off, 16);
    if (part == 0) en1024[col] = s * 1024.0f;
    if (t == 0) *loss_slot = 0.0f;
}

// ---- main: no-LDS streaming MFMA + top-2 + fused exact recheck ----
// grid 512 (2 blocks/CU), block 256 = 4 waves; block owns 64 rows;
// wave w: all 64 rows (rt=4) x 256 cols (col-tiles w*16 .. w*16+15).
__global__ __launch_bounds__(256, 2) void vq_main(const float* __restrict__ x,
                                                  const short8* __restrict__ Ef,
                                                  const float* __restrict__ en1024,
                                                  const float* __restrict__ emb,
                                                  float* __restrict__ outq,
                                                  float* __restrict__ loss_slot) {
    __shared__ int2  sTop[4][64];
    __shared__ float lsum[4];

    const int t = threadIdx.x;
    const int w = t >> 6;
    const int lane = t & 63;
    const int l15 = lane & 15;
    const int quad = lane >> 4;
    const size_t rbase = (size_t)blockIdx.x * 64;

    // A fragments: 64 rows (4 row-tiles), bf16 hi/lo, register-resident (128 VGPRs)
    short8 ahi[4][4], alo[4][4];
    #pragma unroll
    for (int rt = 0; rt < 4; ++rt)
        #pragma unroll
        for (int kc = 0; kc < 4; ++kc) {
            const float* src = x + (rbase + rt * 16 + l15) * D + (kc * 4 + quad) * 8;
            float4 a = *(const float4*)src;
            float4 b = *(const float4*)(src + 4);
            float xv[8] = {a.x, a.y, a.z, a.w, b.x, b.y, b.z, b.w};
            short8 sh, sl;
            #pragma unroll
            for (int j = 0; j < 8; ++j) {
                float f = xv[j];
                unsigned short hb = f2bf(f);
                float hf = __uint_as_float(((unsigned)hb) << 16);
                sh[j] = (short)hb;
                sl[j] = (short)f2bf(f - hf);
            }
            ahi[rt][kc] = sh;
            alo[rt][kc] = sl;
        }

    // packed top-2 keys: 16 slots = 4 rt x 4 acc regs
    int k1[16], k2[16];
    #pragma unroll
    for (int s = 0; s < 16; ++s) { k1[s] = 0x7fffffff; k2[s] = 0x7fffffff; }

    for (int i = 0; i < 16; ++i) {
        const int ct = w * 16 + i;
        const short8* bp = Ef + ct * 512 + lane;
        const int colbase = ct * 16 + l15;
        float enk = en1024[colbase];
        short8 bh[4], bl[4];
        #pragma unroll
        for (int kc = 0; kc < 4; ++kc) {
            bh[kc] = bp[kc * 128];        // coalesced 1KB global loads, L2-hot
            bl[kc] = bp[kc * 128 + 64];
        }
        f32x4 acc[4] = {{0.f,0.f,0.f,0.f},{0.f,0.f,0.f,0.f},
                        {0.f,0.f,0.f,0.f},{0.f,0.f,0.f,0.f}};
        #pragma unroll
        for (int kc = 0; kc < 4; ++kc) {   // 12 groups of 4 independent chains
            #pragma unroll
            for (int rt = 0; rt < 4; ++rt)
                acc[rt] = __builtin_amdgcn_mfma_f32_16x16x32_bf16(ahi[rt][kc], bh[kc], acc[rt], 0, 0, 0);
            #pragma unroll
            for (int rt = 0; rt < 4; ++rt)
                acc[rt] = __builtin_amdgcn_mfma_f32_16x16x32_bf16(ahi[rt][kc], bl[kc], acc[rt], 0, 0, 0);
            #pragma unroll
            for (int rt = 0; rt < 4; ++rt)
                acc[rt] = __builtin_amdgcn_mfma_f32_16x16x32_bf16(alo[rt][kc], bh[kc], acc[rt], 0, 0, 0);
        }
        #pragma unroll
        for (int rt = 0; rt < 4; ++rt)
            #pragma unroll
            for (int r = 0; r < 4; ++r) {
                int kk = (int)(enk - 2048.0f * acc[rt][r]);   // trunc: monotone
                int key = (kk << 10) + colbase;               // np tie-break in low bits
                int s = rt * 4 + r;
                int mx = k1[s] > key ? k1[s] : key;
                k1[s] = k1[s] < key ? k1[s] : key;
                k2[s] = k2[s] < mx ? k2[s] : mx;
            }
    }

    // merge top-2 across the 16 lanes of each quad-row; publish per wave
    #pragma unroll
    for (int s = 0; s < 16; ++s) {
        int a1 = k1[s], a2 = k2[s];
        #pragma unroll
        for (int m = 1; m < 16; m <<= 1) {
            int o1 = __shfl_xor(a1, m, 16);
            int o2 = __shfl_xor(a2, m, 16);
            int mx  = a1 > o1 ? a1 : o1;
            int mn2 = a2 < o2 ? a2 : o2;
            a1 = a1 < o1 ? a1 : o1;
            a2 = mx < mn2 ? mx : mn2;
        }
        if (l15 == 0) sTop[w][(s >> 2) * 16 + quad * 4 + (s & 3)] = make_int2(a1, a2);
    }
    __syncthreads();   // only barrier in the kernel

    // fused epilogue: cross-wave merge, exact fp32 recheck, gather q, loss
    float lacc = 0.0f;
    #pragma unroll
    for (int rep = 0; rep < 2; ++rep) {
        int rib = rep * 32 + (t >> 3);       // 32 rows/pass, 8 lanes/row
        int l8 = t & 7;
        size_t row = rbase + rib;

        int a1 = sTop[0][rib].x, a2 = sTop[0][rib].y;
        #pragma unroll
        for (int j = 1; j < 4; ++j) {
            int b1 = sTop[j][rib].x, b2 = sTop[j][rib].y;
            int mx  = a1 > b1 ? a1 : b1;
            int mn2 = a2 < b2 ? a2 : b2;
            a1 = a1 < b1 ? a1 : b1;
            a2 = mx < mn2 ? mx : mn2;
        }
        int c1 = a1 & 1023, c2 = a2 & 1023;

        const float4* xp = (const float4*)(x + row * D + l8 * 16);
        const float4* e1p = (const float4*)(emb + (size_t)c1 * D + l8 * 16);
        const float4* e2p = (const float4*)(emb + (size_t)c2 * D + l8 * 16);
        float4 xs[4] = {xp[0], xp[1], xp[2], xp[3]};
        float4 e1[4] = {e1p[0], e1p[1], e1p[2], e1p[3]};
        float4 e2[4] = {e2p[0], e2p[1], e2p[2], e2p[3]};
        float d1 = 0.f, d2 = 0.f;
        #pragma unroll
        for (int j = 0; j < 4; ++j) {
            float dx = e1[j].x - xs[j].x, dy = e1[j].y - xs[j].y,
                  dz = e1[j].z - xs[j].z, dw = e1[j].w - xs[j].w;
            d1 += dx * dx + dy * dy + dz * dz + dw * dw;
            dx = e2[j].x - xs[j].x; dy = e2[j].y - xs[j].y;
            dz = e2[j].z - xs[j].z; dw = e2[j].w - xs[j].w;
            d2 += dx * dx + dy * dy + dz * dz + dw * dw;
        }
        #pragma unroll
        for (int off = 4; off; off >>= 1) {
            d1 += __shfl_xor(d1, off, 8);
            d2 += __shfl_xor(d2, off, 8);
        }
        bool w2 = (d2 < d1) || (d2 == d1 && c2 < c1);
        float bd = w2 ? d2 : d1;
        float4* dst = (float4*)(outq + row * D + l8 * 16);
        #pragma unroll
        for (int j = 0; j < 4; ++j) dst[j] = w2 ? e2[j] : e1[j];
        if (l8 == 0) lacc += bd;
    }
    #pragma unroll
    for (int off = 32; off; off >>= 1) lacc += __shfl_down(lacc, off, 64);
    if (lane == 0) lsum[w] = lacc;
    __syncthreads();
    if (t == 0) atomicAdd(loss_slot, 1.5f * ((lsum[0] + lsum[1]) + (lsum[2] + lsum[3])));
}

extern "C" void kernel_launch(void* const* d_in, const int* in_sizes, int n_in,
                              void* d_out, int out_size, void* d_ws, size_t ws_size,
                              hipStream_t stream) {
    const float* x   = (const float*)d_in[0];   // [32768,128]
    const float* emb = (const float*)d_in[1];   // [1024,128]
    float* outq      = (float*)d_out;
    float* loss_slot = outq + (size_t)N_ROWS * D;

    char* ws = (char*)d_ws;
    short8* Ef    = (short8*)(ws + WS_EF);
    float* en1024 = (float*)(ws + WS_EN);

    vq_prep<<<64, 256, 0, stream>>>(emb, Ef, en1024, loss_slot);
    vq_main<<<512, 256, 0, stream>>>(x, Ef, en1024, emb, outq, loss_slot);
}

// Round 5
// 98.461 us; speedup vs baseline: 1.2679x; 1.2679x over previous
//
#include <hip/hip_runtime.h>

typedef __attribute__((ext_vector_type(8))) short short8;
typedef __attribute__((ext_vector_type(4))) float f32x4;

#define N_ROWS 32768
#define D 128
#define K_EMB 1024
#define BIAS 512.0f   // keeps score = ||e||^2 - 2x.e + BIAS > 0 (||x||^2 << 512 whp)

// ws: Ef bf16 fragment-linear (256 KB) + enb (4 KB)
#define WS_EF 0
#define WS_ENB (K_EMB * D * 2)

__device__ __forceinline__ unsigned short f2bf(float f) {
    unsigned u = __float_as_uint(f);
    u += 0x7fffu + ((u >> 16) & 1u);   // RNE to bf16
    return (unsigned short)(u >> 16);
}

// ---- prep: emb -> fragment-linear bf16 + (||e||^2 + BIAS) ; zero loss ----
// short8 index: ct*256 + kc*64 + lane  (lane = quad*16 + l15)
// holds E[col = ct*16+l15][dims kc*32 + quad*8 .. +8]  (MFMA B-operand layout)
__global__ __launch_bounds__(256) void vq_prep(const float* __restrict__ emb,
                                               short8* __restrict__ Ef,
                                               float* __restrict__ enb,
                                               float* __restrict__ loss_slot) {
    int t = blockIdx.x * 256 + threadIdx.x;   // 16384: 1024 cols x 16 parts
    int col = t >> 4, part = t & 15;          // dims part*8 .. part*8+8
    int kc = part >> 2, quad = part & 3;
    int ct = col >> 4, l15 = col & 15;

    const float4* e4 = (const float4*)(emb + (size_t)col * D + part * 8);
    float4 a = e4[0], b = e4[1];
    float xv[8] = {a.x, a.y, a.z, a.w, b.x, b.y, b.z, b.w};
    short8 sh;
    float s = 0.0f;
    #pragma unroll
    for (int j = 0; j < 8; ++j) {
        float f = xv[j];
        s += f * f;
        sh[j] = (short)f2bf(f);
    }
    Ef[ct * 256 + kc * 64 + quad * 16 + l15] = sh;
    #pragma unroll
    for (int off = 8; off; off >>= 1) s += __shfl_down(s, off, 16);
    if (part == 0) enb[col] = s + BIAS;
    if (t == 0) *loss_slot = 0.0f;
}

// ---- main: streaming bf16 MFMA + packed-key top-2 + fused exact recheck ----
// grid 512 (2 blocks/CU), block 256 = 4 waves; block owns 64 rows (rt=4/wave);
// wave w sweeps col-tiles w*16 .. w*16+15 (256 cols). B streamed global->VGPR.
__global__ __launch_bounds__(256, 2) void vq_main(const float* __restrict__ x,
                                                  const short8* __restrict__ Ef,
                                                  const float* __restrict__ enb,
                                                  const float* __restrict__ emb,
                                                  float* __restrict__ outq,
                                                  float* __restrict__ loss_slot) {
    __shared__ float Xs[64 * 132];   // fp32 x rows, stride 132 (conflict-free)
    __shared__ uint2 sTop[4][64];
    __shared__ float lsum[4];

    const int t = threadIdx.x;
    const int w = t >> 6;
    const int lane = t & 63;
    const int l15 = lane & 15;
    const int quad = lane >> 4;
    const size_t rbase = (size_t)blockIdx.x * 64;

    // stage x tile (64 rows x 128 fp32) into LDS, coalesced
    {
        const float4* xg = (const float4*)(x + rbase * D);
        #pragma unroll
        for (int i = 0; i < 8; ++i) {
            int f = t + i * 256;             // 0..2047 float4s
            int r = f >> 5, c4 = f & 31;
            *(float4*)&Xs[r * 132 + c4 * 4] = xg[f];
        }
    }
    __syncthreads();

    // A fragments (bf16, single product): 4 row-tiles x 4 k-chunks = 64 VGPRs
    short8 afr[4][4];
    #pragma unroll
    for (int rt = 0; rt < 4; ++rt)
        #pragma unroll
        for (int kc = 0; kc < 4; ++kc) {
            const float* sp = &Xs[(rt * 16 + l15) * 132 + kc * 32 + quad * 8];
            float4 a = *(const float4*)sp;
            float4 b = *(const float4*)(sp + 4);
            float xv[8] = {a.x, a.y, a.z, a.w, b.x, b.y, b.z, b.w};
            short8 sh;
            #pragma unroll
            for (int j = 0; j < 8; ++j) sh[j] = (short)f2bf(xv[j]);
            afr[rt][kc] = sh;
        }

    // packed-key top-2: score fp32 with col in low 10 mantissa bits
    float k1[16], k2[16];
    #pragma unroll
    for (int s = 0; s < 16; ++s) { k1[s] = 3.0e38f; k2[s] = 3.0e38f; }

    // B double-buffer (global -> VGPR, 1KB coalesced per load, L2-hot)
    const short8* bp = Ef + (size_t)(w * 16) * 256 + lane;
    short8 b0 = bp[0], b1 = bp[64], b2 = bp[128], b3 = bp[192];

    #pragma unroll 2
    for (int i = 0; i < 16; ++i) {
        const int ct = w * 16 + i;
        const int colbase = ct * 16 + l15;
        float enk = enb[colbase];
        short8 n0, n1, n2, n3;
        if (i < 15) {
            const short8* np = Ef + (size_t)(ct + 1) * 256 + lane;
            n0 = np[0]; n1 = np[64]; n2 = np[128]; n3 = np[192];
        }
        f32x4 acc[4] = {{0.f,0.f,0.f,0.f},{0.f,0.f,0.f,0.f},
                        {0.f,0.f,0.f,0.f},{0.f,0.f,0.f,0.f}};
        #pragma unroll
        for (int rt = 0; rt < 4; ++rt)
            acc[rt] = __builtin_amdgcn_mfma_f32_16x16x32_bf16(afr[rt][0], b0, acc[rt], 0, 0, 0);
        #pragma unroll
        for (int rt = 0; rt < 4; ++rt)
            acc[rt] = __builtin_amdgcn_mfma_f32_16x16x32_bf16(afr[rt][1], b1, acc[rt], 0, 0, 0);
        #pragma unroll
        for (int rt = 0; rt < 4; ++rt)
            acc[rt] = __builtin_amdgcn_mfma_f32_16x16x32_bf16(afr[rt][2], b2, acc[rt], 0, 0, 0);
        #pragma unroll
        for (int rt = 0; rt < 4; ++rt)
            acc[rt] = __builtin_amdgcn_mfma_f32_16x16x32_bf16(afr[rt][3], b3, acc[rt], 0, 0, 0);

        #pragma unroll
        for (int rt = 0; rt < 4; ++rt)
            #pragma unroll
            for (int r = 0; r < 4; ++r) {
                float s = fmaf(acc[rt][r], -2.0f, enk);             // > 0 by BIAS
                unsigned key = (__float_as_uint(s) & 0xFFFFFC00u) | (unsigned)colbase;
                float kf = __uint_as_float(key);                    // monotone, tie->low col
                int sl = rt * 4 + r;
                k2[sl] = __builtin_amdgcn_fmed3f(k1[sl], k2[sl], kf);
                k1[sl] = fminf(k1[sl], kf);
            }
        b0 = n0; b1 = n1; b2 = n2; b3 = n3;
    }

    // merge sorted pairs across the 16 lanes of each quad-row
    #pragma unroll
    for (int s = 0; s < 16; ++s) {
        float a1 = k1[s], a2 = k2[s];
        #pragma unroll
        for (int m = 1; m < 16; m <<= 1) {
            float o1 = __shfl_xor(a1, m, 16);
            float o2 = __shfl_xor(a2, m, 16);
            float mx = fmaxf(a1, o1);
            a1 = fminf(a1, o1);
            a2 = fminf(mx, fminf(a2, o2));
        }
        if (l15 == 0) {
            int rib = (s >> 2) * 16 + quad * 4 + (s & 3);
            sTop[w][rib] = make_uint2(__float_as_uint(a1), __float_as_uint(a2));
        }
    }
    __syncthreads();

    // fused epilogue: cross-wave merge, exact fp32 recheck (x from LDS), gather, loss
    float lacc = 0.0f;
    #pragma unroll
    for (int rep = 0; rep < 2; ++rep) {
        int rib = rep * 32 + (t >> 3);       // 32 rows/pass, 8 lanes/row
        int l8 = t & 7;
        size_t row = rbase + rib;

        float a1 = __uint_as_float(sTop[0][rib].x);
        float a2 = __uint_as_float(sTop[0][rib].y);
        #pragma unroll
        for (int j = 1; j < 4; ++j) {
            float b1 = __uint_as_float(sTop[j][rib].x);
            float b2 = __uint_as_float(sTop[j][rib].y);
            float mx = fmaxf(a1, b1);
            a1 = fminf(a1, b1);
            a2 = fminf(mx, fminf(a2, b2));
        }
        int c1 = __float_as_uint(a1) & 1023, c2 = __float_as_uint(a2) & 1023;

        const float4* e1p = (const float4*)(emb + (size_t)c1 * D + l8 * 16);
        const float4* e2p = (const float4*)(emb + (size_t)c2 * D + l8 * 16);
        float4 e1[4] = {e1p[0], e1p[1], e1p[2], e1p[3]};
        float4 e2[4] = {e2p[0], e2p[1], e2p[2], e2p[3]};
        float4 xs[4];
        #pragma unroll
        for (int j = 0; j < 4; ++j) xs[j] = *(const float4*)&Xs[rib * 132 + l8 * 16 + j * 4];
        float d1 = 0.f, d2 = 0.f;
        #pragma unroll
        for (int j = 0; j < 4; ++j) {
            float dx = e1[j].x - xs[j].x, dy = e1[j].y - xs[j].y,
                  dz = e1[j].z - xs[j].z, dw = e1[j].w - xs[j].w;
            d1 += dx * dx + dy * dy + dz * dz + dw * dw;
            dx = e2[j].x - xs[j].x; dy = e2[j].y - xs[j].y;
            dz = e2[j].z - xs[j].z; dw = e2[j].w - xs[j].w;
            d2 += dx * dx + dy * dy + dz * dz + dw * dw;
        }
        #pragma unroll
        for (int off = 4; off; off >>= 1) {
            d1 += __shfl_xor(d1, off, 8);
            d2 += __shfl_xor(d2, off, 8);
        }
        bool w2 = (d2 < d1) || (d2 == d1 && c2 < c1);   // np tie-break: lowest idx
        float bd = w2 ? d2 : d1;
        float4* dst = (float4*)(outq + row * D + l8 * 16);
        #pragma unroll
        for (int j = 0; j < 4; ++j) dst[j] = w2 ? e2[j] : e1[j];
        if (l8 == 0) lacc += bd;
    }
    #pragma unroll
    for (int off = 32; off; off >>= 1) lacc += __shfl_down(lacc, off, 64);
    if (lane == 0) lsum[w] = lacc;
    __syncthreads();
    if (t == 0) atomicAdd(loss_slot, 1.5f * ((lsum[0] + lsum[1]) + (lsum[2] + lsum[3])));
}

extern "C" void kernel_launch(void* const* d_in, const int* in_sizes, int n_in,
                              void* d_out, int out_size, void* d_ws, size_t ws_size,
                              hipStream_t stream) {
    const float* x   = (const float*)d_in[0];   // [32768,128]
    const float* emb = (const float*)d_in[1];   // [1024,128]
    float* outq      = (float*)d_out;
    float* loss_slot = outq + (size_t)N_ROWS * D;

    char* ws = (char*)d_ws;
    short8* Ef = (short8*)(ws + WS_EF);
    float* enb = (float*)(ws + WS_ENB);

    vq_prep<<<64, 256, 0, stream>>>(emb, Ef, enb, loss_slot);
    vq_main<<<512, 256, 0, stream>>>(x, Ef, enb, emb, outq, loss_slot);
}